// Round 6
// baseline (162.682 us; speedup 1.0000x reference)
//
#include <hip/hip_runtime.h>

#define T 512
#define B 2
#define NH 16
#define FD 16
#define HD 64
#define DP 160
#define CH 64
#define NC 8

typedef __attribute__((ext_vector_type(4))) short short4v;
typedef __attribute__((ext_vector_type(8))) short bf16x8;
typedef __attribute__((ext_vector_type(4))) float f32x4;

__constant__ unsigned char c_iu[120] = {
0,0,0,0,0,0,0,0,0,0,0,0,0,0,0,
1,1,1,1,1,1,1,1,1,1,1,1,1,1,
2,2,2,2,2,2,2,2,2,2,2,2,2,
3,3,3,3,3,3,3,3,3,3,3,3,
4,4,4,4,4,4,4,4,4,4,4,
5,5,5,5,5,5,5,5,5,5,
6,6,6,6,6,6,6,6,6,
7,7,7,7,7,7,7,7,
8,8,8,8,8,8,8,
9,9,9,9,9,9,
10,10,10,10,10,
11,11,11,11,
12,12,12,
13,13,
14};
__constant__ unsigned char c_ju[120] = {
1,2,3,4,5,6,7,8,9,10,11,12,13,14,15,
2,3,4,5,6,7,8,9,10,11,12,13,14,15,
3,4,5,6,7,8,9,10,11,12,13,14,15,
4,5,6,7,8,9,10,11,12,13,14,15,
5,6,7,8,9,10,11,12,13,14,15,
6,7,8,9,10,11,12,13,14,15,
7,8,9,10,11,12,13,14,15,
8,9,10,11,12,13,14,15,
9,10,11,12,13,14,15,
10,11,12,13,14,15,
11,12,13,14,15,
12,13,14,15,
13,14,15,
14,15,
15};

__device__ inline unsigned short f2bf_rne(float x) {
    unsigned u = __float_as_uint(x);
    u += 0x7fff + ((u >> 16) & 1);
    return (unsigned short)(u >> 16);
}
__device__ inline float bf2f(unsigned short h) {
    return __uint_as_float(((unsigned)h) << 16);
}
__device__ inline f32x4 mfma1(bf16x8 a, bf16x8 b, f32x4 acc) {
    return __builtin_amdgcn_mfma_f32_16x16x32_bf16(a, b, acc, 0, 0, 0);
}
__device__ inline f32x4 mfma3(bf16x8 ah, bf16x8 al, bf16x8 bh, bf16x8 bl, f32x4 acc) {
    acc = __builtin_amdgcn_mfma_f32_16x16x32_bf16(ah, bh, acc, 0, 0, 0);
    acc = __builtin_amdgcn_mfma_f32_16x16x32_bf16(ah, bl, acc, 0, 0, 0);
    acc = __builtin_amdgcn_mfma_f32_16x16x32_bf16(al, bh, acc, 0, 0, 0);
    return acc;
}

// compute features D = q4*40 .. q4*40+39 of one token (x = 16 fp32) into bf16 row
__device__ inline void feat40(const float* __restrict__ x, int q4,
                              unsigned short* __restrict__ dst) {
    #pragma unroll
    for (int g = 0; g < 10; ++g) {
        short4v s;
        #pragma unroll
        for (int e = 0; e < 4; ++e) {
            const int D = q4 * 40 + g * 4 + e;
            float f;
            if (D == 0)       f = 1.f;
            else if (D < 17)  f = x[D-1] * 0.5f;
            else if (D < 33)  { float a = x[D-17]; f = a * a * 0.17677669529663687f; }
            else if (D < 153) { int p = D - 33; f = x[c_iu[p]] * x[c_ju[p]] * 0.25f; }
            else              f = 0.f;
            s[e] = (short)f2bf_rne(f);
        }
        *(short4v*)(dst + q4 * 40 + g * 4) = s;
    }
}

// ---- 1) preconv: split hs/Wc to hi/lo, Wo to hi only; zero Cp and out ----
__global__ __launch_bounds__(256)
void preconv(const float* __restrict__ hs, const float* __restrict__ Wq,
             const float* __restrict__ Wk, const float* __restrict__ Wv,
             const float* __restrict__ Wo,
             short* __restrict__ hsh, short* __restrict__ hsl,
             short* __restrict__ Wch, short* __restrict__ Wcl,
             short* __restrict__ Woh,
             float* __restrict__ Cp, float* __restrict__ outz) {
    const int i4 = blockIdx.x * 256 + threadIdx.x;
    if (i4 >= 917504) {   // zero-fill region
        const int z = i4 - 917504;
        float4 zf = make_float4(0.f, 0.f, 0.f, 0.f);
        if (z < 393216) *(float4*)(Cp + (size_t)z * 4) = zf;
        else            *(float4*)(outz + (size_t)(z - 393216) * 4) = zf;
        return;
    }
    const float* src; short *dh, *dl; size_t off4;
    if (i4 < 262144)      { src = hs; dh = hsh;          dl = hsl;          off4 = i4; }
    else if (i4 < 327680) { src = Wq; dh = Wch;          dl = Wcl;          off4 = i4 - 262144; }
    else if (i4 < 393216) { src = Wk; dh = Wch + 262144; dl = Wcl + 262144; off4 = i4 - 327680; }
    else if (i4 < 655360) { src = Wv; dh = Wch + 524288; dl = Wcl + 524288; off4 = i4 - 393216; }
    else                  { src = Wo; dh = Woh;          dl = nullptr;      off4 = i4 - 655360; }
    float4 v = *(const float4*)(src + off4 * 4);
    float vv[4] = {v.x, v.y, v.z, v.w};
    short4v sh, sl;
    #pragma unroll
    for (int e = 0; e < 4; ++e) {
        unsigned short h = f2bf_rne(vv[e]);
        sh[e] = (short)h;
        sl[e] = (short)f2bf_rne(vv[e] - bf2f(h));
    }
    *(short4v*)(dh + off4 * 4) = sh;
    if (dl) *(short4v*)(dl + off4 * 4) = sl;
}

// ---- 2) proj: Cp[1024][1536] += hs @ Wc^T, split-K2, pipelined, atomic ----
__global__ __launch_bounds__(256)
void gemm_proj(const short* __restrict__ Ah, const short* __restrict__ Al,
               const short* __restrict__ Bh, const short* __restrict__ Bl,
               float* __restrict__ C) {
    __shared__ short sAh[64][40], sAl[64][40], sBh[64][40], sBl[64][40];
    const int tid = threadIdx.x;
    const int bm = blockIdx.y * 64, bn = blockIdx.x * 64, kb = blockIdx.z * 512;
    const int lane = tid & 63, w = tid >> 6;
    const int wm = (w & 1) * 32, wn = (w >> 1) * 32;
    const int srow = tid >> 2, skq = (tid & 3) * 8;
    const int fm = lane & 15, fk = (lane >> 4) * 8;
    f32x4 acc[2][2] = {};
    const short* pAh = Ah + (size_t)(bm + srow) * 1024 + kb + skq;
    const short* pAl = Al + (size_t)(bm + srow) * 1024 + kb + skq;
    const short* pBh = Bh + (size_t)(bn + srow) * 1024 + kb + skq;
    const short* pBl = Bl + (size_t)(bn + srow) * 1024 + kb + skq;
    bf16x8 vah = *(const bf16x8*)pAh, val = *(const bf16x8*)pAl;
    bf16x8 vbh = *(const bf16x8*)pBh, vbl = *(const bf16x8*)pBl;
    for (int k0 = 0; k0 < 512; k0 += 32) {
        __syncthreads();
        *(bf16x8*)&sAh[srow][skq] = vah;
        *(bf16x8*)&sAl[srow][skq] = val;
        *(bf16x8*)&sBh[srow][skq] = vbh;
        *(bf16x8*)&sBl[srow][skq] = vbl;
        __syncthreads();
        const int kn = (k0 + 32 < 512) ? k0 + 32 : k0;   // prefetch next (in flight over MFMA)
        vah = *(const bf16x8*)(pAh + kn);
        val = *(const bf16x8*)(pAl + kn);
        vbh = *(const bf16x8*)(pBh + kn);
        vbl = *(const bf16x8*)(pBl + kn);
        bf16x8 ah[2], al[2], bh2[2], bl2[2];
        #pragma unroll
        for (int i = 0; i < 2; ++i) {
            ah[i]  = *(const bf16x8*)&sAh[wm + i*16 + fm][fk];
            al[i]  = *(const bf16x8*)&sAl[wm + i*16 + fm][fk];
            bh2[i] = *(const bf16x8*)&sBh[wn + i*16 + fm][fk];
            bl2[i] = *(const bf16x8*)&sBl[wn + i*16 + fm][fk];
        }
        #pragma unroll
        for (int i = 0; i < 2; ++i)
            #pragma unroll
            for (int j = 0; j < 2; ++j)
                acc[i][j] = mfma3(ah[i], al[i], bh2[j], bl2[j], acc[i][j]);
    }
    const int crow0 = (lane >> 4) * 4, ccol = lane & 15;
    #pragma unroll
    for (int i = 0; i < 2; ++i)
        #pragma unroll
        for (int j = 0; j < 2; ++j)
            #pragma unroll
            for (int r = 0; r < 4; ++r)
                atomicAdd(&C[(size_t)(bm + wm + i*16 + crow0 + r) * 1536 + bn + wn + j*16 + ccol],
                          acc[i][j][r]);
}

// ---- 3) chunk_state: features in-LDS; S[d][D], z[D] ----
__global__ __launch_bounds__(256)
void chunk_state(const float* __restrict__ Cp, float* __restrict__ S, float* __restrict__ Z) {
    const int bh = blockIdx.x >> 3, c = blockIdx.x & 7;
    const int b = bh >> 4, h = bh & 15;
    const int tid = threadIdx.x;
    const int lane = tid & 63, w = tid >> 6;
    const int wm = (w & 1) * 32, wn = (w >> 1) * 80;
    const int fm = lane & 15, fk = (lane >> 4) * 8;
    __shared__ __align__(16) float sKP[64][17];
    __shared__ __align__(16) unsigned short sK[64][164];   // Kf bf16 [t][D]
    __shared__ __align__(16) unsigned short sV[64][68];    // V bf16 [t][d]
    const int r = tid >> 2, q4 = tid & 3;
    const size_t rowbase = (size_t)(b*T + c*CH + r) * 1536;
    *(float4*)&sKP[r][q4*4] = *(const float4*)(Cp + rowbase + 256 + h*16 + q4*4);
    {
        const float* vsrc = Cp + rowbase + 512 + h*HD + q4*16;
        float vf[16];
        *(float4*)&vf[0]  = *(const float4*)(vsrc + 0);
        *(float4*)&vf[4]  = *(const float4*)(vsrc + 4);
        *(float4*)&vf[8]  = *(const float4*)(vsrc + 8);
        *(float4*)&vf[12] = *(const float4*)(vsrc + 12);
        #pragma unroll
        for (int p = 0; p < 4; ++p) {
            short4v s;
            #pragma unroll
            for (int e = 0; e < 4; ++e) s[e] = (short)f2bf_rne(vf[p*4 + e]);
            *(short4v*)&sV[r][q4*16 + p*4] = s;
        }
    }
    __syncthreads();
    feat40(sKP[r], q4, (unsigned short*)sK[r]);
    __syncthreads();
    if (tid < DP) {
        float zz = 0.f;
        for (int tt = 0; tt < CH; ++tt) zz += bf2f(sK[tt][tid]);
        Z[((size_t)(bh*NC + c)) * DP + tid] = zz;
    }
    f32x4 acc[2][5] = {};
    #pragma unroll
    for (int k0 = 0; k0 < 64; k0 += 32) {
        bf16x8 a[2];
        #pragma unroll
        for (int i = 0; i < 2; ++i) {
            union { bf16x8 v; unsigned short u[8]; } g;
            #pragma unroll
            for (int e = 0; e < 8; ++e) g.u[e] = sV[k0 + fk + e][wm + i*16 + fm];
            a[i] = g.v;
        }
        #pragma unroll
        for (int j = 0; j < 5; ++j) {
            union { bf16x8 v; unsigned short u[8]; } g;
            #pragma unroll
            for (int e = 0; e < 8; ++e) g.u[e] = sK[k0 + fk + e][wn + j*16 + fm];
            #pragma unroll
            for (int i = 0; i < 2; ++i)
                acc[i][j] = mfma1(a[i], g.v, acc[i][j]);
        }
    }
    const int crow0 = (lane >> 4) * 4, ccol = lane & 15;
    float* Sb = S + ((size_t)(bh*NC + c)) * CH * DP;
    #pragma unroll
    for (int i = 0; i < 2; ++i)
        #pragma unroll
        for (int j = 0; j < 5; ++j)
            #pragma unroll
            for (int rr = 0; rr < 4; ++rr)
                Sb[(size_t)(wm + i*16 + crow0 + rr) * DP + wn + j*16 + ccol] = acc[i][j][rr];
}

// ---- 4) chunk_out: features in-LDS, P/A bf16 in-LDS; writes Y bf16 ----
__global__ __launch_bounds__(256)
void chunk_out(const float* __restrict__ Cp, const float* __restrict__ S,
               const float* __restrict__ Z, short* __restrict__ Y) {
    const int bh = blockIdx.x >> 3, c = blockIdx.x & 7;
    const int b = bh >> 4, h = bh & 15;
    const int tid = threadIdx.x;
    const int lane = tid & 63, w = tid >> 6;
    const int wm = (w & 1) * 32, wn = (w >> 1) * 32;
    const int fm = lane & 15, fk = (lane >> 4) * 8;
    __shared__ __align__(16) float sQP[64][17], sKP[64][17];
    __shared__ __align__(16) unsigned short sQf[64][168], sKf[64][168], sPb[64][168];
    __shared__ __align__(16) unsigned short sAb[64][68], sV[64][68];
    __shared__ float sZp[DP];
    __shared__ float sDen[64];
    const int r = tid >> 2, q4 = tid & 3;
    const size_t rowbase = (size_t)(b*T + c*CH + r) * 1536;
    *(float4*)&sQP[r][q4*4] = *(const float4*)(Cp + rowbase + h*16 + q4*4);
    *(float4*)&sKP[r][q4*4] = *(const float4*)(Cp + rowbase + 256 + h*16 + q4*4);
    {
        const float* vsrc = Cp + rowbase + 512 + h*HD + q4*16;
        float vf[16];
        *(float4*)&vf[0]  = *(const float4*)(vsrc + 0);
        *(float4*)&vf[4]  = *(const float4*)(vsrc + 4);
        *(float4*)&vf[8]  = *(const float4*)(vsrc + 8);
        *(float4*)&vf[12] = *(const float4*)(vsrc + 12);
        #pragma unroll
        for (int p = 0; p < 4; ++p) {
            short4v s;
            #pragma unroll
            for (int e = 0; e < 4; ++e) s[e] = (short)f2bf_rne(vf[p*4 + e]);
            *(short4v*)&sV[r][q4*16 + p*4] = s;
        }
    }
    if (tid < DP) {
        float zz = 0.f;
        for (int cc = 0; cc < c; ++cc) zz += Z[((size_t)(bh*NC + cc)) * DP + tid];
        sZp[tid] = zz;
    }
    __syncthreads();
    feat40(sQP[r], q4, (unsigned short*)sQf[r]);
    feat40(sKP[r], q4, (unsigned short*)sKf[r]);
    for (int e = tid; e < 2560; e += 256) {
        const int d = e / 40, D4 = (e % 40) * 4;
        float4 a = make_float4(0.f, 0.f, 0.f, 0.f);
        for (int cc = 0; cc < c; ++cc) {
            float4 s = *(const float4*)(S + (((size_t)(bh*NC + cc)) * CH + d) * DP + D4);
            a.x += s.x; a.y += s.y; a.z += s.z; a.w += s.w;
        }
        short4v s4;
        s4[0] = (short)f2bf_rne(a.x); s4[1] = (short)f2bf_rne(a.y);
        s4[2] = (short)f2bf_rne(a.z); s4[3] = (short)f2bf_rne(a.w);
        *(short4v*)&sPb[d][D4] = s4;
    }
    __syncthreads();
    f32x4 accA[2][2] = {};
    f32x4 accI[2][2] = {};
    for (int k0 = 0; k0 < DP; k0 += 32) {
        bf16x8 qv[2];
        #pragma unroll
        for (int i = 0; i < 2; ++i)
            qv[i] = *(const bf16x8*)&sQf[wm + i*16 + fm][k0 + fk];
        #pragma unroll
        for (int j = 0; j < 2; ++j) {
            bf16x8 kv = *(const bf16x8*)&sKf[wn + j*16 + fm][k0 + fk];
            bf16x8 pv = *(const bf16x8*)&sPb[wn + j*16 + fm][k0 + fk];
            #pragma unroll
            for (int i = 0; i < 2; ++i) {
                accA[i][j] = mfma1(qv[i], kv, accA[i][j]);
                accI[i][j] = mfma1(qv[i], pv, accI[i][j]);
            }
        }
    }
    // den_inter
    {
        float dp = 0.f;
        #pragma unroll
        for (int g = 0; g < 5; ++g) {
            bf16x8 v = *(const bf16x8*)&sQf[r][q4*40 + g*8];
            #pragma unroll
            for (int e = 0; e < 8; ++e)
                dp += bf2f((unsigned short)v[e]) * sZp[q4*40 + g*8 + e];
        }
        dp += __shfl_xor(dp, 1);
        dp += __shfl_xor(dp, 2);
        if (q4 == 0) sDen[r] = dp;
    }
    // masked A -> bf16 LDS
    const int crow0 = (lane >> 4) * 4, ccol = lane & 15;
    #pragma unroll
    for (int i = 0; i < 2; ++i)
        #pragma unroll
        for (int j = 0; j < 2; ++j)
            #pragma unroll
            for (int rr = 0; rr < 4; ++rr) {
                const int t_ = wm + i*16 + crow0 + rr, s_ = wn + j*16 + ccol;
                sAb[t_][s_] = (s_ <= t_) ? f2bf_rne(accA[i][j][rr]) : 0;
            }
    __syncthreads();
    if (tid < 64) {
        float rs = 0.f;
        for (int s_ = 0; s_ < CH; ++s_) rs += bf2f(sAb[tid][s_]);
        sDen[tid] += rs;
    }
    __syncthreads();
    // intra: y += A @ V
    #pragma unroll
    for (int k0 = 0; k0 < 64; k0 += 32) {
        bf16x8 a[2];
        #pragma unroll
        for (int i = 0; i < 2; ++i)
            a[i] = *(const bf16x8*)&sAb[wm + i*16 + fm][k0 + fk];
        #pragma unroll
        for (int j = 0; j < 2; ++j) {
            union { bf16x8 v; unsigned short u[8]; } g;
            #pragma unroll
            for (int e = 0; e < 8; ++e) g.u[e] = sV[k0 + fk + e][wn + j*16 + fm];
            #pragma unroll
            for (int i = 0; i < 2; ++i)
                accI[i][j] = mfma1(a[i], g.v, accI[i][j]);
        }
    }
    // epilogue
    #pragma unroll
    for (int i = 0; i < 2; ++i)
        #pragma unroll
        for (int rr = 0; rr < 4; ++rr) {
            const int t_ = wm + i*16 + crow0 + rr;
            const float inv = 1.f / (sDen[t_] + 1e-12f);
            const size_t grow = (size_t)(b*T + c*CH + t_) * 1024 + h*HD;
            #pragma unroll
            for (int j = 0; j < 2; ++j)
                Y[grow + wn + j*16 + ccol] = (short)f2bf_rne(accI[i][j][rr] * inv);
        }
}

// ---- 5) out GEMM: out += Y @ Woh^T, split-K4, pipelined, atomic ----
__global__ __launch_bounds__(256)
void gemm_out(const short* __restrict__ A, const short* __restrict__ Bm,
              float* __restrict__ C) {
    __shared__ short sA[64][40], sB[64][40];
    const int tid = threadIdx.x;
    const int bm = blockIdx.y * 64, bn = blockIdx.x * 64, kb = blockIdx.z * 256;
    const int lane = tid & 63, w = tid >> 6;
    const int wm = (w & 1) * 32, wn = (w >> 1) * 32;
    const int srow = tid >> 2, skq = (tid & 3) * 8;
    const int fm = lane & 15, fk = (lane >> 4) * 8;
    f32x4 acc[2][2] = {};
    const short* pA = A  + (size_t)(bm + srow) * 1024 + kb + skq;
    const short* pB = Bm + (size_t)(bn + srow) * 1024 + kb + skq;
    bf16x8 va = *(const bf16x8*)pA;
    bf16x8 vb = *(const bf16x8*)pB;
    for (int k0 = 0; k0 < 256; k0 += 32) {
        __syncthreads();
        *(bf16x8*)&sA[srow][skq] = va;
        *(bf16x8*)&sB[srow][skq] = vb;
        __syncthreads();
        const int kn = (k0 + 32 < 256) ? k0 + 32 : k0;
        va = *(const bf16x8*)(pA + kn);
        vb = *(const bf16x8*)(pB + kn);
        bf16x8 a[2], b2[2];
        #pragma unroll
        for (int i = 0; i < 2; ++i) {
            a[i]  = *(const bf16x8*)&sA[wm + i*16 + fm][fk];
            b2[i] = *(const bf16x8*)&sB[wn + i*16 + fm][fk];
        }
        #pragma unroll
        for (int i = 0; i < 2; ++i)
            #pragma unroll
            for (int j = 0; j < 2; ++j)
                acc[i][j] = mfma1(a[i], b2[j], acc[i][j]);
    }
    const int crow0 = (lane >> 4) * 4, ccol = lane & 15;
    #pragma unroll
    for (int i = 0; i < 2; ++i)
        #pragma unroll
        for (int j = 0; j < 2; ++j)
            #pragma unroll
            for (int r = 0; r < 4; ++r)
                atomicAdd(&C[(size_t)(bm + wm + i*16 + crow0 + r) * 1024 + bn + wn + j*16 + ccol],
                          acc[i][j][r]);
}

extern "C" void kernel_launch(void* const* d_in, const int* in_sizes, int n_in,
                              void* d_out, int out_size, void* d_ws, size_t ws_size,
                              hipStream_t stream) {
    const float* hs = (const float*)d_in[0];
    const float* Wq = (const float*)d_in[1];
    const float* Wk = (const float*)d_in[2];
    const float* Wv = (const float*)d_in[3];
    const float* Wo = (const float*)d_in[4];
    float* out = (float*)d_out;

    char* p = (char*)d_ws;
    float* Cp  = (float*)p; p += (size_t)1024*1536*4;
    short* hsh = (short*)p; p += (size_t)1048576*2;
    short* hsl = (short*)p; p += (size_t)1048576*2;
    short* Wch = (short*)p; p += (size_t)1536*1024*2;
    short* Wcl = (short*)p; p += (size_t)1536*1024*2;
    short* Woh = (short*)p; p += (size_t)1048576*2;
    float* S   = (float*)p; p += (size_t)32*NC*CH*DP*4;
    float* Z   = (float*)p; p += (size_t)32*NC*DP*4;
    short* Y   = (short*)p; p += (size_t)1048576*2;

    dim3 blk(256);
    preconv<<<dim3(6144), blk, 0, stream>>>(hs, Wq, Wk, Wv, Wo, hsh, hsl, Wch, Wcl, Woh, Cp, out);
    gemm_proj<<<dim3(24, 16, 2), blk, 0, stream>>>(hsh, hsl, Wch, Wcl, Cp);
    chunk_state<<<dim3(256), blk, 0, stream>>>(Cp, S, Z);
    chunk_out<<<dim3(256), blk, 0, stream>>>(Cp, S, Z, Y);
    gemm_out<<<dim3(16, 16, 4), blk, 0, stream>>>(Y, Woh, out);
}

// Round 7
// 150.058 us; speedup vs baseline: 1.0841x; 1.0841x over previous
//
#include <hip/hip_runtime.h>

#define T 512
#define B 2
#define NH 16
#define FD 16
#define HD 64
#define DP 160
#define CH 64
#define NC 8

typedef __attribute__((ext_vector_type(4))) short short4v;
typedef __attribute__((ext_vector_type(8))) short bf16x8;
typedef __attribute__((ext_vector_type(4))) float f32x4;

__constant__ unsigned char c_iu[120] = {
0,0,0,0,0,0,0,0,0,0,0,0,0,0,0,
1,1,1,1,1,1,1,1,1,1,1,1,1,1,
2,2,2,2,2,2,2,2,2,2,2,2,2,
3,3,3,3,3,3,3,3,3,3,3,3,
4,4,4,4,4,4,4,4,4,4,4,
5,5,5,5,5,5,5,5,5,5,
6,6,6,6,6,6,6,6,6,
7,7,7,7,7,7,7,7,
8,8,8,8,8,8,8,
9,9,9,9,9,9,
10,10,10,10,10,
11,11,11,11,
12,12,12,
13,13,
14};
__constant__ unsigned char c_ju[120] = {
1,2,3,4,5,6,7,8,9,10,11,12,13,14,15,
2,3,4,5,6,7,8,9,10,11,12,13,14,15,
3,4,5,6,7,8,9,10,11,12,13,14,15,
4,5,6,7,8,9,10,11,12,13,14,15,
5,6,7,8,9,10,11,12,13,14,15,
6,7,8,9,10,11,12,13,14,15,
7,8,9,10,11,12,13,14,15,
8,9,10,11,12,13,14,15,
9,10,11,12,13,14,15,
10,11,12,13,14,15,
11,12,13,14,15,
12,13,14,15,
13,14,15,
14,15,
15};

__device__ inline unsigned short f2bf_rne(float x) {
    unsigned u = __float_as_uint(x);
    u += 0x7fff + ((u >> 16) & 1);
    return (unsigned short)(u >> 16);
}
__device__ inline float bf2f(unsigned short h) {
    return __uint_as_float(((unsigned)h) << 16);
}
__device__ inline f32x4 mfma1(bf16x8 a, bf16x8 b, f32x4 acc) {
    return __builtin_amdgcn_mfma_f32_16x16x32_bf16(a, b, acc, 0, 0, 0);
}

// compute features D = q4*40 .. q4*40+39 of one token (x = 16 fp32) into bf16 row
__device__ inline void feat40(const float* __restrict__ x, int q4,
                              unsigned short* __restrict__ dst) {
    #pragma unroll
    for (int g = 0; g < 10; ++g) {
        short4v s;
        #pragma unroll
        for (int e = 0; e < 4; ++e) {
            const int D = q4 * 40 + g * 4 + e;
            float f;
            if (D == 0)       f = 1.f;
            else if (D < 17)  f = x[D-1] * 0.5f;
            else if (D < 33)  { float a = x[D-17]; f = a * a * 0.17677669529663687f; }
            else if (D < 153) { int p = D - 33; f = x[c_iu[p]] * x[c_ju[p]] * 0.25f; }
            else              f = 0.f;
            s[e] = (short)f2bf_rne(f);
        }
        *(short4v*)(dst + q4 * 40 + g * 4) = s;
    }
}

// ---- 1) preconv: hs -> hi/lo; Wq|Wk|Wv -> Wch (hi only); Wo -> Woh (hi only) ----
__global__ __launch_bounds__(256)
void preconv(const float* __restrict__ hs, const float* __restrict__ Wq,
             const float* __restrict__ Wk, const float* __restrict__ Wv,
             const float* __restrict__ Wo,
             short* __restrict__ hsh, short* __restrict__ hsl,
             short* __restrict__ Wch, short* __restrict__ Woh) {
    const int i4 = blockIdx.x * 256 + threadIdx.x;   // 917504 float4s total
    const float* src; short *dh, *dl; size_t off4;
    if (i4 < 262144)      { src = hs; dh = hsh;          dl = hsl;   off4 = i4; }
    else if (i4 < 327680) { src = Wq; dh = Wch;          dl = nullptr; off4 = i4 - 262144; }
    else if (i4 < 393216) { src = Wk; dh = Wch + 262144; dl = nullptr; off4 = i4 - 327680; }
    else if (i4 < 655360) { src = Wv; dh = Wch + 524288; dl = nullptr; off4 = i4 - 393216; }
    else                  { src = Wo; dh = Woh;          dl = nullptr; off4 = i4 - 655360; }
    float4 v = *(const float4*)(src + off4 * 4);
    float vv[4] = {v.x, v.y, v.z, v.w};
    short4v sh, sl;
    #pragma unroll
    for (int e = 0; e < 4; ++e) {
        unsigned short h = f2bf_rne(vv[e]);
        sh[e] = (short)h;
        sl[e] = (short)f2bf_rne(vv[e] - bf2f(h));
    }
    *(short4v*)(dh + off4 * 4) = sh;
    if (dl) *(short4v*)(dl + off4 * 4) = sl;
}

// ---- 2) proj: Cp[1024][1536] = hs @ Wc^T; A split hi/lo (2 MFMA), B single ----
__global__ __launch_bounds__(256)
void gemm_proj(const short* __restrict__ Ah, const short* __restrict__ Al,
               const short* __restrict__ Bm, float* __restrict__ C) {
    __shared__ short sAh[64][40], sAl[64][40], sB[96][40];
    const int tid = threadIdx.x;
    const int bm = blockIdx.y * 64, bn = blockIdx.x * 96;
    const int lane = tid & 63, w = tid >> 6;
    const int wm = (w & 1) * 32, wn = (w >> 1) * 48;
    const int srA = tid >> 2, skA = (tid & 3) * 8;
    const int srB = tid >> 1, skB = (tid & 1) * 16;
    const int fm = lane & 15, fk = (lane >> 4) * 8;
    f32x4 acc[2][3] = {};
    const short* pAh = Ah + (size_t)(bm + srA) * 1024 + skA;
    const short* pAl = Al + (size_t)(bm + srA) * 1024 + skA;
    const short* pB  = Bm + (size_t)(bn + (srB < 96 ? srB : 0)) * 1024 + skB;
    bf16x8 vah = *(const bf16x8*)pAh;
    bf16x8 val = *(const bf16x8*)pAl;
    bf16x8 vb0, vb1;
    if (tid < 192) { vb0 = *(const bf16x8*)pB; vb1 = *(const bf16x8*)(pB + 8); }
    for (int k0 = 0; k0 < 1024; k0 += 32) {
        __syncthreads();
        *(bf16x8*)&sAh[srA][skA] = vah;
        *(bf16x8*)&sAl[srA][skA] = val;
        if (tid < 192) {
            *(bf16x8*)&sB[srB][skB]     = vb0;
            *(bf16x8*)&sB[srB][skB + 8] = vb1;
        }
        __syncthreads();
        const int kn = (k0 + 32 < 1024) ? k0 + 32 : k0;
        vah = *(const bf16x8*)(pAh + kn);
        val = *(const bf16x8*)(pAl + kn);
        if (tid < 192) { vb0 = *(const bf16x8*)(pB + kn); vb1 = *(const bf16x8*)(pB + kn + 8); }
        bf16x8 ah[2], al[2];
        #pragma unroll
        for (int i = 0; i < 2; ++i) {
            ah[i] = *(const bf16x8*)&sAh[wm + i*16 + fm][fk];
            al[i] = *(const bf16x8*)&sAl[wm + i*16 + fm][fk];
        }
        #pragma unroll
        for (int j = 0; j < 3; ++j) {
            bf16x8 b = *(const bf16x8*)&sB[wn + j*16 + fm][fk];
            #pragma unroll
            for (int i = 0; i < 2; ++i) {
                acc[i][j] = mfma1(ah[i], b, acc[i][j]);
                acc[i][j] = mfma1(al[i], b, acc[i][j]);
            }
        }
    }
    const int crow0 = (lane >> 4) * 4, ccol = lane & 15;
    #pragma unroll
    for (int i = 0; i < 2; ++i)
        #pragma unroll
        for (int j = 0; j < 3; ++j)
            #pragma unroll
            for (int r = 0; r < 4; ++r)
                C[(size_t)(bm + wm + i*16 + crow0 + r) * 1536 + bn + wn + j*16 + ccol] = acc[i][j][r];
}

// ---- 3) chunk_state: features in-LDS; S[d][D], z[D] ----
__global__ __launch_bounds__(256)
void chunk_state(const float* __restrict__ Cp, float* __restrict__ S, float* __restrict__ Z) {
    const int bh = blockIdx.x >> 3, c = blockIdx.x & 7;
    const int b = bh >> 4, h = bh & 15;
    const int tid = threadIdx.x;
    const int lane = tid & 63, w = tid >> 6;
    const int wm = (w & 1) * 32, wn = (w >> 1) * 80;
    const int fm = lane & 15, fk = (lane >> 4) * 8;
    __shared__ __align__(16) float sKP[64][17];
    __shared__ __align__(16) unsigned short sK[64][164];
    __shared__ __align__(16) unsigned short sV[64][68];
    const int r = tid >> 2, q4 = tid & 3;
    const size_t rowbase = (size_t)(b*T + c*CH + r) * 1536;
    *(float4*)&sKP[r][q4*4] = *(const float4*)(Cp + rowbase + 256 + h*16 + q4*4);
    {
        const float* vsrc = Cp + rowbase + 512 + h*HD + q4*16;
        float vf[16];
        *(float4*)&vf[0]  = *(const float4*)(vsrc + 0);
        *(float4*)&vf[4]  = *(const float4*)(vsrc + 4);
        *(float4*)&vf[8]  = *(const float4*)(vsrc + 8);
        *(float4*)&vf[12] = *(const float4*)(vsrc + 12);
        #pragma unroll
        for (int p = 0; p < 4; ++p) {
            short4v s;
            #pragma unroll
            for (int e = 0; e < 4; ++e) s[e] = (short)f2bf_rne(vf[p*4 + e]);
            *(short4v*)&sV[r][q4*16 + p*4] = s;
        }
    }
    __syncthreads();
    feat40(sKP[r], q4, (unsigned short*)sK[r]);
    __syncthreads();
    if (tid < DP) {
        float zz = 0.f;
        for (int tt = 0; tt < CH; ++tt) zz += bf2f(sK[tt][tid]);
        Z[((size_t)(bh*NC + c)) * DP + tid] = zz;
    }
    f32x4 acc[2][5] = {};
    #pragma unroll
    for (int k0 = 0; k0 < 64; k0 += 32) {
        bf16x8 a[2];
        #pragma unroll
        for (int i = 0; i < 2; ++i) {
            union { bf16x8 v; unsigned short u[8]; } g;
            #pragma unroll
            for (int e = 0; e < 8; ++e) g.u[e] = sV[k0 + fk + e][wm + i*16 + fm];
            a[i] = g.v;
        }
        #pragma unroll
        for (int j = 0; j < 5; ++j) {
            union { bf16x8 v; unsigned short u[8]; } g;
            #pragma unroll
            for (int e = 0; e < 8; ++e) g.u[e] = sK[k0 + fk + e][wn + j*16 + fm];
            #pragma unroll
            for (int i = 0; i < 2; ++i)
                acc[i][j] = mfma1(a[i], g.v, acc[i][j]);
        }
    }
    const int crow0 = (lane >> 4) * 4, ccol = lane & 15;
    float* Sb = S + ((size_t)(bh*NC + c)) * CH * DP;
    #pragma unroll
    for (int i = 0; i < 2; ++i)
        #pragma unroll
        for (int j = 0; j < 5; ++j)
            #pragma unroll
            for (int rr = 0; rr < 4; ++rr)
                Sb[(size_t)(wm + i*16 + crow0 + rr) * DP + wn + j*16 + ccol] = acc[i][j][rr];
}

// ---- 4) chunk_out: features in-LDS, P/A bf16 in-LDS; writes Y bf16 ----
__global__ __launch_bounds__(256)
void chunk_out(const float* __restrict__ Cp, const float* __restrict__ S,
               const float* __restrict__ Z, short* __restrict__ Y) {
    const int bh = blockIdx.x >> 3, c = blockIdx.x & 7;
    const int b = bh >> 4, h = bh & 15;
    const int tid = threadIdx.x;
    const int lane = tid & 63, w = tid >> 6;
    const int wm = (w & 1) * 32, wn = (w >> 1) * 32;
    const int fm = lane & 15, fk = (lane >> 4) * 8;
    __shared__ __align__(16) float sQP[64][17], sKP[64][17];
    __shared__ __align__(16) unsigned short sQf[64][168], sKf[64][168], sPb[64][168];
    __shared__ __align__(16) unsigned short sAb[64][68], sV[64][68];
    __shared__ float sZp[DP];
    __shared__ float sDen[64];
    const int r = tid >> 2, q4 = tid & 3;
    const size_t rowbase = (size_t)(b*T + c*CH + r) * 1536;
    *(float4*)&sQP[r][q4*4] = *(const float4*)(Cp + rowbase + h*16 + q4*4);
    *(float4*)&sKP[r][q4*4] = *(const float4*)(Cp + rowbase + 256 + h*16 + q4*4);
    {
        const float* vsrc = Cp + rowbase + 512 + h*HD + q4*16;
        float vf[16];
        *(float4*)&vf[0]  = *(const float4*)(vsrc + 0);
        *(float4*)&vf[4]  = *(const float4*)(vsrc + 4);
        *(float4*)&vf[8]  = *(const float4*)(vsrc + 8);
        *(float4*)&vf[12] = *(const float4*)(vsrc + 12);
        #pragma unroll
        for (int p = 0; p < 4; ++p) {
            short4v s;
            #pragma unroll
            for (int e = 0; e < 4; ++e) s[e] = (short)f2bf_rne(vf[p*4 + e]);
            *(short4v*)&sV[r][q4*16 + p*4] = s;
        }
    }
    if (tid < DP) {
        float zz = 0.f;
        for (int cc = 0; cc < c; ++cc) zz += Z[((size_t)(bh*NC + cc)) * DP + tid];
        sZp[tid] = zz;
    }
    __syncthreads();
    feat40(sQP[r], q4, (unsigned short*)sQf[r]);
    feat40(sKP[r], q4, (unsigned short*)sKf[r]);
    for (int e = tid; e < 2560; e += 256) {
        const int d = e / 40, D4 = (e % 40) * 4;
        float4 a = make_float4(0.f, 0.f, 0.f, 0.f);
        for (int cc = 0; cc < c; ++cc) {
            float4 s = *(const float4*)(S + (((size_t)(bh*NC + cc)) * CH + d) * DP + D4);
            a.x += s.x; a.y += s.y; a.z += s.z; a.w += s.w;
        }
        short4v s4;
        s4[0] = (short)f2bf_rne(a.x); s4[1] = (short)f2bf_rne(a.y);
        s4[2] = (short)f2bf_rne(a.z); s4[3] = (short)f2bf_rne(a.w);
        *(short4v*)&sPb[d][D4] = s4;
    }
    __syncthreads();
    f32x4 accA[2][2] = {};
    f32x4 accI[2][2] = {};
    for (int k0 = 0; k0 < DP; k0 += 32) {
        bf16x8 qv[2];
        #pragma unroll
        for (int i = 0; i < 2; ++i)
            qv[i] = *(const bf16x8*)&sQf[wm + i*16 + fm][k0 + fk];
        #pragma unroll
        for (int j = 0; j < 2; ++j) {
            bf16x8 kv = *(const bf16x8*)&sKf[wn + j*16 + fm][k0 + fk];
            bf16x8 pv = *(const bf16x8*)&sPb[wn + j*16 + fm][k0 + fk];
            #pragma unroll
            for (int i = 0; i < 2; ++i) {
                accA[i][j] = mfma1(qv[i], kv, accA[i][j]);
                accI[i][j] = mfma1(qv[i], pv, accI[i][j]);
            }
        }
    }
    // den_inter
    {
        float dp = 0.f;
        #pragma unroll
        for (int g = 0; g < 5; ++g) {
            bf16x8 v = *(const bf16x8*)&sQf[r][q4*40 + g*8];
            #pragma unroll
            for (int e = 0; e < 8; ++e)
                dp += bf2f((unsigned short)v[e]) * sZp[q4*40 + g*8 + e];
        }
        dp += __shfl_xor(dp, 1);
        dp += __shfl_xor(dp, 2);
        if (q4 == 0) sDen[r] = dp;
    }
    // masked A -> bf16 LDS
    const int crow0 = (lane >> 4) * 4, ccol = lane & 15;
    #pragma unroll
    for (int i = 0; i < 2; ++i)
        #pragma unroll
        for (int j = 0; j < 2; ++j)
            #pragma unroll
            for (int rr = 0; rr < 4; ++rr) {
                const int t_ = wm + i*16 + crow0 + rr, s_ = wn + j*16 + ccol;
                sAb[t_][s_] = (s_ <= t_) ? f2bf_rne(accA[i][j][rr]) : 0;
            }
    __syncthreads();
    if (tid < 64) {
        float rs = 0.f;
        for (int s_ = 0; s_ < CH; ++s_) rs += bf2f(sAb[tid][s_]);
        sDen[tid] += rs;
    }
    __syncthreads();
    // intra: y += A @ V
    #pragma unroll
    for (int k0 = 0; k0 < 64; k0 += 32) {
        bf16x8 a[2];
        #pragma unroll
        for (int i = 0; i < 2; ++i)
            a[i] = *(const bf16x8*)&sAb[wm + i*16 + fm][k0 + fk];
        #pragma unroll
        for (int j = 0; j < 2; ++j) {
            union { bf16x8 v; unsigned short u[8]; } g;
            #pragma unroll
            for (int e = 0; e < 8; ++e) g.u[e] = sV[k0 + fk + e][wn + j*16 + fm];
            #pragma unroll
            for (int i = 0; i < 2; ++i)
                accI[i][j] = mfma1(a[i], g.v, accI[i][j]);
        }
    }
    // epilogue
    #pragma unroll
    for (int i = 0; i < 2; ++i)
        #pragma unroll
        for (int rr = 0; rr < 4; ++rr) {
            const int t_ = wm + i*16 + crow0 + rr;
            const float inv = 1.f / (sDen[t_] + 1e-12f);
            const size_t grow = (size_t)(b*T + c*CH + t_) * 1024 + h*HD;
            #pragma unroll
            for (int j = 0; j < 2; ++j)
                Y[grow + wn + j*16 + ccol] = (short)f2bf_rne(accI[i][j][rr] * inv);
        }
}

// ---- 5) out GEMM: out = Y @ Woh^T, single bf16, pipelined, direct store ----
__global__ __launch_bounds__(256)
void gemm_out(const short* __restrict__ A, const short* __restrict__ Bm,
              float* __restrict__ C) {
    __shared__ short sA[64][40], sB[64][40];
    const int tid = threadIdx.x;
    const int bm = blockIdx.y * 64, bn = blockIdx.x * 64;
    const int lane = tid & 63, w = tid >> 6;
    const int wm = (w & 1) * 32, wn = (w >> 1) * 32;
    const int srow = tid >> 2, skq = (tid & 3) * 8;
    const int fm = lane & 15, fk = (lane >> 4) * 8;
    f32x4 acc[2][2] = {};
    const short* pA = A  + (size_t)(bm + srow) * 1024 + skq;
    const short* pB = Bm + (size_t)(bn + srow) * 1024 + skq;
    bf16x8 va = *(const bf16x8*)pA;
    bf16x8 vb = *(const bf16x8*)pB;
    for (int k0 = 0; k0 < 1024; k0 += 32) {
        __syncthreads();
        *(bf16x8*)&sA[srow][skq] = va;
        *(bf16x8*)&sB[srow][skq] = vb;
        __syncthreads();
        const int kn = (k0 + 32 < 1024) ? k0 + 32 : k0;
        va = *(const bf16x8*)(pA + kn);
        vb = *(const bf16x8*)(pB + kn);
        bf16x8 a[2], b2[2];
        #pragma unroll
        for (int i = 0; i < 2; ++i) {
            a[i]  = *(const bf16x8*)&sA[wm + i*16 + fm][fk];
            b2[i] = *(const bf16x8*)&sB[wn + i*16 + fm][fk];
        }
        #pragma unroll
        for (int i = 0; i < 2; ++i)
            #pragma unroll
            for (int j = 0; j < 2; ++j)
                acc[i][j] = mfma1(a[i], b2[j], acc[i][j]);
    }
    const int crow0 = (lane >> 4) * 4, ccol = lane & 15;
    #pragma unroll
    for (int i = 0; i < 2; ++i)
        #pragma unroll
        for (int j = 0; j < 2; ++j)
            #pragma unroll
            for (int r = 0; r < 4; ++r)
                C[(size_t)(bm + wm + i*16 + crow0 + r) * 1024 + bn + wn + j*16 + ccol] = acc[i][j][r];
}

extern "C" void kernel_launch(void* const* d_in, const int* in_sizes, int n_in,
                              void* d_out, int out_size, void* d_ws, size_t ws_size,
                              hipStream_t stream) {
    const float* hs = (const float*)d_in[0];
    const float* Wq = (const float*)d_in[1];
    const float* Wk = (const float*)d_in[2];
    const float* Wv = (const float*)d_in[3];
    const float* Wo = (const float*)d_in[4];
    float* out = (float*)d_out;

    char* p = (char*)d_ws;
    float* Cp  = (float*)p; p += (size_t)1024*1536*4;
    short* hsh = (short*)p; p += (size_t)1048576*2;
    short* hsl = (short*)p; p += (size_t)1048576*2;
    short* Wch = (short*)p; p += (size_t)1536*1024*2;
    short* Woh = (short*)p; p += (size_t)1048576*2;
    float* S   = (float*)p; p += (size_t)32*NC*CH*DP*4;
    float* Z   = (float*)p; p += (size_t)32*NC*DP*4;
    short* Y   = (short*)p; p += (size_t)1048576*2;

    dim3 blk(256);
    preconv<<<dim3(3584), blk, 0, stream>>>(hs, Wq, Wk, Wv, Wo, hsh, hsl, Wch, Woh);
    gemm_proj<<<dim3(16, 16), blk, 0, stream>>>(hsh, hsl, Wch, Cp);
    chunk_state<<<dim3(256), blk, 0, stream>>>(Cp, S, Z);
    chunk_out<<<dim3(256), blk, 0, stream>>>(Cp, S, Z, Y);
    gemm_out<<<dim3(16, 16), blk, 0, stream>>>(Y, Woh, out);
}

// Round 8
// 136.242 us; speedup vs baseline: 1.1941x; 1.1014x over previous
//
#include <hip/hip_runtime.h>

#define T 512
#define B 2
#define NH 16
#define FD 16
#define HD 64
#define DP 160
#define CH 64
#define NC 8

typedef __attribute__((ext_vector_type(4))) short short4v;
typedef __attribute__((ext_vector_type(8))) short bf16x8;
typedef __attribute__((ext_vector_type(4))) float f32x4;

__constant__ unsigned char c_iu[120] = {
0,0,0,0,0,0,0,0,0,0,0,0,0,0,0,
1,1,1,1,1,1,1,1,1,1,1,1,1,1,
2,2,2,2,2,2,2,2,2,2,2,2,2,
3,3,3,3,3,3,3,3,3,3,3,3,
4,4,4,4,4,4,4,4,4,4,4,
5,5,5,5,5,5,5,5,5,5,
6,6,6,6,6,6,6,6,6,
7,7,7,7,7,7,7,7,
8,8,8,8,8,8,8,
9,9,9,9,9,9,
10,10,10,10,10,
11,11,11,11,
12,12,12,
13,13,
14};
__constant__ unsigned char c_ju[120] = {
1,2,3,4,5,6,7,8,9,10,11,12,13,14,15,
2,3,4,5,6,7,8,9,10,11,12,13,14,15,
3,4,5,6,7,8,9,10,11,12,13,14,15,
4,5,6,7,8,9,10,11,12,13,14,15,
5,6,7,8,9,10,11,12,13,14,15,
6,7,8,9,10,11,12,13,14,15,
7,8,9,10,11,12,13,14,15,
8,9,10,11,12,13,14,15,
9,10,11,12,13,14,15,
10,11,12,13,14,15,
11,12,13,14,15,
12,13,14,15,
13,14,15,
14,15,
15};

__device__ inline unsigned short f2bf_rne(float x) {
    unsigned u = __float_as_uint(x);
    u += 0x7fff + ((u >> 16) & 1);
    return (unsigned short)(u >> 16);
}
__device__ inline float bf2f(unsigned short h) {
    return __uint_as_float(((unsigned)h) << 16);
}
__device__ inline f32x4 mfma1(bf16x8 a, bf16x8 b, f32x4 acc) {
    return __builtin_amdgcn_mfma_f32_16x16x32_bf16(a, b, acc, 0, 0, 0);
}

__device__ inline void feat40(const float* __restrict__ x, int q4,
                              unsigned short* __restrict__ dst) {
    #pragma unroll
    for (int g = 0; g < 10; ++g) {
        short4v s;
        #pragma unroll
        for (int e = 0; e < 4; ++e) {
            const int D = q4 * 40 + g * 4 + e;
            float f;
            if (D == 0)       f = 1.f;
            else if (D < 17)  f = x[D-1] * 0.5f;
            else if (D < 33)  { float a = x[D-17]; f = a * a * 0.17677669529663687f; }
            else if (D < 153) { int p = D - 33; f = x[c_iu[p]] * x[c_ju[p]] * 0.25f; }
            else              f = 0.f;
            s[e] = (short)f2bf_rne(f);
        }
        *(short4v*)(dst + q4 * 40 + g * 4) = s;
    }
}

// ---- 1) preconv ----
__global__ __launch_bounds__(256)
void preconv(const float* __restrict__ hs, const float* __restrict__ Wq,
             const float* __restrict__ Wk, const float* __restrict__ Wv,
             const float* __restrict__ Wo,
             short* __restrict__ hsh, short* __restrict__ hsl,
             short* __restrict__ Wch, short* __restrict__ Woh) {
    const int i4 = blockIdx.x * 256 + threadIdx.x;
    const float* src; short *dh, *dl; size_t off4;
    if (i4 < 262144)      { src = hs; dh = hsh;          dl = hsl;     off4 = i4; }
    else if (i4 < 327680) { src = Wq; dh = Wch;          dl = nullptr; off4 = i4 - 262144; }
    else if (i4 < 393216) { src = Wk; dh = Wch + 262144; dl = nullptr; off4 = i4 - 327680; }
    else if (i4 < 655360) { src = Wv; dh = Wch + 524288; dl = nullptr; off4 = i4 - 393216; }
    else                  { src = Wo; dh = Woh;          dl = nullptr; off4 = i4 - 655360; }
    float4 v = *(const float4*)(src + off4 * 4);
    float vv[4] = {v.x, v.y, v.z, v.w};
    short4v sh, sl;
    #pragma unroll
    for (int e = 0; e < 4; ++e) {
        unsigned short h = f2bf_rne(vv[e]);
        sh[e] = (short)h;
        sl[e] = (short)f2bf_rne(vv[e] - bf2f(h));
    }
    *(short4v*)(dh + off4 * 4) = sh;
    if (dl) *(short4v*)(dl + off4 * 4) = sl;
}

// ---- 2) proj: Cp = hs @ Wc^T; A hi/lo (2 MFMA), B single; double-buffered LDS ----
__global__ __launch_bounds__(256)
void gemm_proj(const short* __restrict__ Ah, const short* __restrict__ Al,
               const short* __restrict__ Bm, float* __restrict__ C) {
    __shared__ short sAh[2][64][40], sAl[2][64][40], sB[2][96][40];  // 35.8 KB
    const int tid = threadIdx.x;
    const int bm = blockIdx.y * 64, bn = blockIdx.x * 96;
    const int lane = tid & 63, w = tid >> 6;
    const int wm = (w & 1) * 32, wn = (w >> 1) * 48;
    const int srA = tid >> 2, skA = (tid & 3) * 8;
    const int srB = tid >> 1, skB = (tid & 1) * 16;
    const int fm = lane & 15, fk = (lane >> 4) * 8;
    f32x4 acc[2][3] = {};
    const short* pAh = Ah + (size_t)(bm + srA) * 1024 + skA;
    const short* pAl = Al + (size_t)(bm + srA) * 1024 + skA;
    const short* pB  = Bm + (size_t)(bn + (srB < 96 ? srB : 0)) * 1024 + skB;
    // stage tile 0 into buf 0
    bf16x8 vah = *(const bf16x8*)pAh;
    bf16x8 val = *(const bf16x8*)pAl;
    bf16x8 vb0, vb1;
    if (tid < 192) { vb0 = *(const bf16x8*)pB; vb1 = *(const bf16x8*)(pB + 8); }
    *(bf16x8*)&sAh[0][srA][skA] = vah;
    *(bf16x8*)&sAl[0][srA][skA] = val;
    if (tid < 192) { *(bf16x8*)&sB[0][srB][skB] = vb0; *(bf16x8*)&sB[0][srB][skB+8] = vb1; }
    // preload tile 1 into regs
    vah = *(const bf16x8*)(pAh + 32);
    val = *(const bf16x8*)(pAl + 32);
    if (tid < 192) { vb0 = *(const bf16x8*)(pB + 32); vb1 = *(const bf16x8*)(pB + 40); }
    __syncthreads();
    for (int k0 = 0; k0 < 1024; k0 += 32) {
        const int b = (k0 >> 5) & 1;
        // frag reads from buf b (issue first)
        bf16x8 ah[2], al[2], bfr[3];
        #pragma unroll
        for (int i = 0; i < 2; ++i) {
            ah[i] = *(const bf16x8*)&sAh[b][wm + i*16 + fm][fk];
            al[i] = *(const bf16x8*)&sAl[b][wm + i*16 + fm][fk];
        }
        #pragma unroll
        for (int j = 0; j < 3; ++j)
            bfr[j] = *(const bf16x8*)&sB[b][wn + j*16 + fm][fk];
        // write tile k+1 into buf b^1
        if (k0 + 32 < 1024) {
            *(bf16x8*)&sAh[b^1][srA][skA] = vah;
            *(bf16x8*)&sAl[b^1][srA][skA] = val;
            if (tid < 192) {
                *(bf16x8*)&sB[b^1][srB][skB]   = vb0;
                *(bf16x8*)&sB[b^1][srB][skB+8] = vb1;
            }
        }
        // issue global loads for tile k+2
        if (k0 + 64 < 1024) {
            vah = *(const bf16x8*)(pAh + k0 + 64);
            val = *(const bf16x8*)(pAl + k0 + 64);
            if (tid < 192) { vb0 = *(const bf16x8*)(pB + k0 + 64); vb1 = *(const bf16x8*)(pB + k0 + 72); }
        }
        #pragma unroll
        for (int j = 0; j < 3; ++j)
            #pragma unroll
            for (int i = 0; i < 2; ++i) {
                acc[i][j] = mfma1(ah[i], bfr[j], acc[i][j]);
                acc[i][j] = mfma1(al[i], bfr[j], acc[i][j]);
            }
        __syncthreads();
    }
    const int crow0 = (lane >> 4) * 4, ccol = lane & 15;
    #pragma unroll
    for (int i = 0; i < 2; ++i)
        #pragma unroll
        for (int j = 0; j < 3; ++j)
            #pragma unroll
            for (int r = 0; r < 4; ++r)
                C[(size_t)(bm + wm + i*16 + crow0 + r) * 1536 + bn + wn + j*16 + ccol] = acc[i][j][r];
}

// ---- 3) chunk_state: features in-LDS; S (bf16), z[D] ----
__global__ __launch_bounds__(256)
void chunk_state(const float* __restrict__ Cp, short* __restrict__ S, float* __restrict__ Z) {
    const int bh = blockIdx.x >> 3, c = blockIdx.x & 7;
    const int b = bh >> 4, h = bh & 15;
    const int tid = threadIdx.x;
    const int lane = tid & 63, w = tid >> 6;
    const int wm = (w & 1) * 32, wn = (w >> 1) * 80;
    const int fm = lane & 15, fk = (lane >> 4) * 8;
    __shared__ __align__(16) float sKP[64][17];
    __shared__ __align__(16) unsigned short sK[64][164];
    __shared__ __align__(16) unsigned short sV[64][68];
    const int r = tid >> 2, q4 = tid & 3;
    const size_t rowbase = (size_t)(b*T + c*CH + r) * 1536;
    *(float4*)&sKP[r][q4*4] = *(const float4*)(Cp + rowbase + 256 + h*16 + q4*4);
    {
        const float* vsrc = Cp + rowbase + 512 + h*HD + q4*16;
        float vf[16];
        *(float4*)&vf[0]  = *(const float4*)(vsrc + 0);
        *(float4*)&vf[4]  = *(const float4*)(vsrc + 4);
        *(float4*)&vf[8]  = *(const float4*)(vsrc + 8);
        *(float4*)&vf[12] = *(const float4*)(vsrc + 12);
        #pragma unroll
        for (int p = 0; p < 4; ++p) {
            short4v s;
            #pragma unroll
            for (int e = 0; e < 4; ++e) s[e] = (short)f2bf_rne(vf[p*4 + e]);
            *(short4v*)&sV[r][q4*16 + p*4] = s;
        }
    }
    __syncthreads();
    feat40(sKP[r], q4, (unsigned short*)sK[r]);
    __syncthreads();
    if (tid < DP) {
        float zz = 0.f;
        for (int tt = 0; tt < CH; ++tt) zz += bf2f(sK[tt][tid]);
        Z[((size_t)(bh*NC + c)) * DP + tid] = zz;
    }
    f32x4 acc[2][5] = {};
    #pragma unroll
    for (int k0 = 0; k0 < 64; k0 += 32) {
        bf16x8 a[2];
        #pragma unroll
        for (int i = 0; i < 2; ++i) {
            union { bf16x8 v; unsigned short u[8]; } g;
            #pragma unroll
            for (int e = 0; e < 8; ++e) g.u[e] = sV[k0 + fk + e][wm + i*16 + fm];
            a[i] = g.v;
        }
        #pragma unroll
        for (int j = 0; j < 5; ++j) {
            union { bf16x8 v; unsigned short u[8]; } g;
            #pragma unroll
            for (int e = 0; e < 8; ++e) g.u[e] = sK[k0 + fk + e][wn + j*16 + fm];
            #pragma unroll
            for (int i = 0; i < 2; ++i)
                acc[i][j] = mfma1(a[i], g.v, acc[i][j]);
        }
    }
    const int crow0 = (lane >> 4) * 4, ccol = lane & 15;
    short* Sb = S + ((size_t)(bh*NC + c)) * CH * DP;
    #pragma unroll
    for (int i = 0; i < 2; ++i)
        #pragma unroll
        for (int j = 0; j < 5; ++j)
            #pragma unroll
            for (int rr = 0; rr < 4; ++rr)
                Sb[(size_t)(wm + i*16 + crow0 + rr) * DP + wn + j*16 + ccol] =
                    (short)f2bf_rne(acc[i][j][rr]);
}

// ---- 4) chunk_out ----
__global__ __launch_bounds__(256)
void chunk_out(const float* __restrict__ Cp, const short* __restrict__ S,
               const float* __restrict__ Z, short* __restrict__ Y) {
    const int bh = blockIdx.x >> 3, c = blockIdx.x & 7;
    const int b = bh >> 4, h = bh & 15;
    const int tid = threadIdx.x;
    const int lane = tid & 63, w = tid >> 6;
    const int wm = (w & 1) * 32, wn = (w >> 1) * 32;
    const int fm = lane & 15, fk = (lane >> 4) * 8;
    __shared__ __align__(16) float sQP[64][17], sKP[64][17];
    __shared__ __align__(16) unsigned short sQf[64][168], sKf[64][168], sPb[64][168];
    __shared__ __align__(16) unsigned short sAb[64][68], sV[64][68];
    __shared__ float sZp[DP];
    __shared__ float sDen[64];
    const int r = tid >> 2, q4 = tid & 3;
    const size_t rowbase = (size_t)(b*T + c*CH + r) * 1536;
    *(float4*)&sQP[r][q4*4] = *(const float4*)(Cp + rowbase + h*16 + q4*4);
    *(float4*)&sKP[r][q4*4] = *(const float4*)(Cp + rowbase + 256 + h*16 + q4*4);
    {
        const float* vsrc = Cp + rowbase + 512 + h*HD + q4*16;
        float vf[16];
        *(float4*)&vf[0]  = *(const float4*)(vsrc + 0);
        *(float4*)&vf[4]  = *(const float4*)(vsrc + 4);
        *(float4*)&vf[8]  = *(const float4*)(vsrc + 8);
        *(float4*)&vf[12] = *(const float4*)(vsrc + 12);
        #pragma unroll
        for (int p = 0; p < 4; ++p) {
            short4v s;
            #pragma unroll
            for (int e = 0; e < 4; ++e) s[e] = (short)f2bf_rne(vf[p*4 + e]);
            *(short4v*)&sV[r][q4*16 + p*4] = s;
        }
    }
    if (tid < DP) {
        float zz = 0.f;
        for (int cc = 0; cc < c; ++cc) zz += Z[((size_t)(bh*NC + cc)) * DP + tid];
        sZp[tid] = zz;
    }
    __syncthreads();
    feat40(sQP[r], q4, (unsigned short*)sQf[r]);
    feat40(sKP[r], q4, (unsigned short*)sKf[r]);
    // prefix of bf16 S -> bf16 P in LDS
    for (int e = tid; e < 1280; e += 256) {
        const int d = e / 20, D8 = (e % 20) * 8;
        float a[8] = {};
        for (int cc = 0; cc < c; ++cc) {
            bf16x8 s = *(const bf16x8*)(S + (((size_t)(bh*NC + cc)) * CH + d) * DP + D8);
            #pragma unroll
            for (int e2 = 0; e2 < 8; ++e2) a[e2] += bf2f((unsigned short)s[e2]);
        }
        bf16x8 o;
        #pragma unroll
        for (int e2 = 0; e2 < 8; ++e2) o[e2] = (short)f2bf_rne(a[e2]);
        *(bf16x8*)&sPb[d][D8] = o;
    }
    __syncthreads();
    f32x4 accA[2][2] = {};
    f32x4 accI[2][2] = {};
    for (int k0 = 0; k0 < DP; k0 += 32) {
        bf16x8 qv[2];
        #pragma unroll
        for (int i = 0; i < 2; ++i)
            qv[i] = *(const bf16x8*)&sQf[wm + i*16 + fm][k0 + fk];
        #pragma unroll
        for (int j = 0; j < 2; ++j) {
            bf16x8 kv = *(const bf16x8*)&sKf[wn + j*16 + fm][k0 + fk];
            bf16x8 pv = *(const bf16x8*)&sPb[wn + j*16 + fm][k0 + fk];
            #pragma unroll
            for (int i = 0; i < 2; ++i) {
                accA[i][j] = mfma1(qv[i], kv, accA[i][j]);
                accI[i][j] = mfma1(qv[i], pv, accI[i][j]);
            }
        }
    }
    // den_inter
    {
        float dp = 0.f;
        #pragma unroll
        for (int g = 0; g < 5; ++g) {
            bf16x8 v = *(const bf16x8*)&sQf[r][q4*40 + g*8];
            #pragma unroll
            for (int e = 0; e < 8; ++e)
                dp += bf2f((unsigned short)v[e]) * sZp[q4*40 + g*8 + e];
        }
        dp += __shfl_xor(dp, 1);
        dp += __shfl_xor(dp, 2);
        if (q4 == 0) sDen[r] = dp;
    }
    // masked A -> bf16 LDS
    const int crow0 = (lane >> 4) * 4, ccol = lane & 15;
    #pragma unroll
    for (int i = 0; i < 2; ++i)
        #pragma unroll
        for (int j = 0; j < 2; ++j)
            #pragma unroll
            for (int rr = 0; rr < 4; ++rr) {
                const int t_ = wm + i*16 + crow0 + rr, s_ = wn + j*16 + ccol;
                sAb[t_][s_] = (s_ <= t_) ? f2bf_rne(accA[i][j][rr]) : 0;
            }
    __syncthreads();
    // den_intra: parallel rowsum (thread (r,q4) sums 16 cols, shuffle-reduce)
    {
        float rs = 0.f;
        #pragma unroll
        for (int s_ = 0; s_ < 16; ++s_) rs += bf2f(sAb[r][q4*16 + s_]);
        rs += __shfl_xor(rs, 1);
        rs += __shfl_xor(rs, 2);
        if (q4 == 0) sDen[r] += rs;
    }
    __syncthreads();
    // intra: y += A @ V
    #pragma unroll
    for (int k0 = 0; k0 < 64; k0 += 32) {
        bf16x8 a[2];
        #pragma unroll
        for (int i = 0; i < 2; ++i)
            a[i] = *(const bf16x8*)&sAb[wm + i*16 + fm][k0 + fk];
        #pragma unroll
        for (int j = 0; j < 2; ++j) {
            union { bf16x8 v; unsigned short u[8]; } g;
            #pragma unroll
            for (int e = 0; e < 8; ++e) g.u[e] = sV[k0 + fk + e][wn + j*16 + fm];
            #pragma unroll
            for (int i = 0; i < 2; ++i)
                accI[i][j] = mfma1(a[i], g.v, accI[i][j]);
        }
    }
    // epilogue
    #pragma unroll
    for (int i = 0; i < 2; ++i)
        #pragma unroll
        for (int rr = 0; rr < 4; ++rr) {
            const int t_ = wm + i*16 + crow0 + rr;
            const float inv = 1.f / (sDen[t_] + 1e-12f);
            const size_t grow = (size_t)(b*T + c*CH + t_) * 1024 + h*HD;
            #pragma unroll
            for (int j = 0; j < 2; ++j)
                Y[grow + wn + j*16 + ccol] = (short)f2bf_rne(accI[i][j][rr] * inv);
        }
}

// ---- 5) out GEMM: out = Y @ Woh^T, single bf16, double-buffered LDS ----
__global__ __launch_bounds__(256)
void gemm_out(const short* __restrict__ A, const short* __restrict__ Bm,
              float* __restrict__ C) {
    __shared__ short sA[2][64][40], sB[2][64][40];  // 20.5 KB
    const int tid = threadIdx.x;
    const int bm = blockIdx.y * 64, bn = blockIdx.x * 64;
    const int lane = tid & 63, w = tid >> 6;
    const int wm = (w & 1) * 32, wn = (w >> 1) * 32;
    const int srow = tid >> 2, skq = (tid & 3) * 8;
    const int fm = lane & 15, fk = (lane >> 4) * 8;
    f32x4 acc[2][2] = {};
    const short* pA = A  + (size_t)(bm + srow) * 1024 + skq;
    const short* pB = Bm + (size_t)(bn + srow) * 1024 + skq;
    bf16x8 va = *(const bf16x8*)pA;
    bf16x8 vb = *(const bf16x8*)pB;
    *(bf16x8*)&sA[0][srow][skq] = va;
    *(bf16x8*)&sB[0][srow][skq] = vb;
    va = *(const bf16x8*)(pA + 32);
    vb = *(const bf16x8*)(pB + 32);
    __syncthreads();
    for (int k0 = 0; k0 < 1024; k0 += 32) {
        const int b = (k0 >> 5) & 1;
        bf16x8 a[2], b2[2];
        #pragma unroll
        for (int i = 0; i < 2; ++i) {
            a[i]  = *(const bf16x8*)&sA[b][wm + i*16 + fm][fk];
            b2[i] = *(const bf16x8*)&sB[b][wn + i*16 + fm][fk];
        }
        if (k0 + 32 < 1024) {
            *(bf16x8*)&sA[b^1][srow][skq] = va;
            *(bf16x8*)&sB[b^1][srow][skq] = vb;
        }
        if (k0 + 64 < 1024) {
            va = *(const bf16x8*)(pA + k0 + 64);
            vb = *(const bf16x8*)(pB + k0 + 64);
        }
        #pragma unroll
        for (int i = 0; i < 2; ++i)
            #pragma unroll
            for (int j = 0; j < 2; ++j)
                acc[i][j] = mfma1(a[i], b2[j], acc[i][j]);
        __syncthreads();
    }
    const int crow0 = (lane >> 4) * 4, ccol = lane & 15;
    #pragma unroll
    for (int i = 0; i < 2; ++i)
        #pragma unroll
        for (int j = 0; j < 2; ++j)
            #pragma unroll
            for (int r = 0; r < 4; ++r)
                C[(size_t)(bm + wm + i*16 + crow0 + r) * 1024 + bn + wn + j*16 + ccol] = acc[i][j][r];
}

extern "C" void kernel_launch(void* const* d_in, const int* in_sizes, int n_in,
                              void* d_out, int out_size, void* d_ws, size_t ws_size,
                              hipStream_t stream) {
    const float* hs = (const float*)d_in[0];
    const float* Wq = (const float*)d_in[1];
    const float* Wk = (const float*)d_in[2];
    const float* Wv = (const float*)d_in[3];
    const float* Wo = (const float*)d_in[4];
    float* out = (float*)d_out;

    char* p = (char*)d_ws;
    float* Cp  = (float*)p; p += (size_t)1024*1536*4;
    short* hsh = (short*)p; p += (size_t)1048576*2;
    short* hsl = (short*)p; p += (size_t)1048576*2;
    short* Wch = (short*)p; p += (size_t)1536*1024*2;
    short* Woh = (short*)p; p += (size_t)1048576*2;
    short* S   = (short*)p; p += (size_t)32*NC*CH*DP*2;
    float* Z   = (float*)p; p += (size_t)32*NC*DP*4;
    short* Y   = (short*)p; p += (size_t)1048576*2;

    dim3 blk(256);
    preconv<<<dim3(3584), blk, 0, stream>>>(hs, Wq, Wk, Wv, Wo, hsh, hsl, Wch, Woh);
    gemm_proj<<<dim3(16, 16), blk, 0, stream>>>(hsh, hsl, Wch, Cp);
    chunk_state<<<dim3(256), blk, 0, stream>>>(Cp, S, Z);
    chunk_out<<<dim3(256), blk, 0, stream>>>(Cp, S, Z, Y);
    gemm_out<<<dim3(16, 16), blk, 0, stream>>>(Y, Woh, out);
}